// Round 1
// baseline (970.228 us; speedup 1.0000x reference)
//
#include <hip/hip_runtime.h>
#include <hip/hip_bf16.h>

// Problem constants (match reference)
#define NB 128          // graphs
#define NN 512          // nodes per graph
#define NF 128          // feature dim
#define BN (NB*NN)      // 65536 total nodes
#define NE (BN*16)      // 1048576 edges
#define WPR 16          // bitmap words per row (512 bits / 32)

// ---------------------------------------------------------------------------
// Adjacency build: bitmap with set-semantics dedup + out-degree count
// ---------------------------------------------------------------------------
__global__ __launch_bounds__(256) void build_adj_kernel(
    const int* __restrict__ src, const int* __restrict__ dst,
    unsigned* __restrict__ bitmap, int* __restrict__ deg)
{
    int e = blockIdx.x * 256 + threadIdx.x;
    int s = src[e];
    int d = dst[e];
    int col = d & (NN - 1);                 // column within graph
    unsigned word = (unsigned)s * WPR + (col >> 5);
    unsigned mask = 1u << (col & 31);
    unsigned old = atomicOr(&bitmap[word], mask);
    if (!(old & mask)) atomicAdd(&deg[s], 1);
}

__global__ __launch_bounds__(256) void dinv_kernel(
    const int* __restrict__ deg, float* __restrict__ dinv)
{
    int i = blockIdx.x * 256 + threadIdx.x;
    int d = deg[i];
    dinv[i] = (d > 0) ? rsqrtf((float)d) : 0.0f;
}

// ---------------------------------------------------------------------------
// SpMM: zout[i,:] = sum_j S[i,j] * zin[j,:],  S[i,j] = dinv_i * dinv_j * A_ij
// acc handling: initAcc!=0 -> acc = xinit + zout   else acc += zout
// one block (128 threads) per row; thread = feature
// ---------------------------------------------------------------------------
__global__ __launch_bounds__(128) void spmm_kernel(
    const float* __restrict__ zin, float* __restrict__ zout,
    float* __restrict__ acc, const float* __restrict__ xinit,
    const unsigned* __restrict__ bitmap, const float* __restrict__ dinv,
    int initAcc)
{
    int row = blockIdx.x;
    int f = threadIdx.x;
    int base = (row >> 9) << 9;             // first node of this graph
    float di = dinv[row];

    float sum = 0.0f;
    #pragma unroll
    for (int w = 0; w < WPR; ++w) {
        unsigned bits = bitmap[(size_t)row * WPR + w];
        while (bits) {
            int j = __ffs(bits) - 1;
            bits &= bits - 1;
            int nbr = base + (w << 5) + j;
            sum += dinv[nbr] * zin[(size_t)nbr * NF + f];
        }
    }
    sum *= di;

    size_t o = (size_t)row * NF + f;
    zout[o] = sum;
    if (initAcc) acc[o] = xinit[o] + sum;
    else         acc[o] += sum;
}

// ---------------------------------------------------------------------------
// GEMM: Y[65536,128] = relu(X @ W[128,128] + b)
// block: 256 threads, 64 rows x 128 cols per block; thread: 4 rows x 8 cols
// W staged in LDS (64 KB)
// ---------------------------------------------------------------------------
__global__ __launch_bounds__(256) void gemm_bias_relu_kernel(
    const float* __restrict__ X, const float* __restrict__ W,
    const float* __restrict__ b, float* __restrict__ Y)
{
    __shared__ float Ws[NF * NF];
    for (int i = threadIdx.x; i < NF * NF / 4; i += 256) {
        ((float4*)Ws)[i] = ((const float4*)W)[i];
    }
    __syncthreads();

    int rg = threadIdx.x >> 4;              // 0..15
    int cg = threadIdx.x & 15;              // 0..15
    int row0 = blockIdx.x * 64 + rg * 4;
    int col0 = cg * 8;

    float acc[4][8];
    #pragma unroll
    for (int r = 0; r < 4; ++r)
        #pragma unroll
        for (int c = 0; c < 8; ++c) acc[r][c] = 0.0f;

    for (int k = 0; k < NF; k += 4) {
        float4 xv[4];
        #pragma unroll
        for (int r = 0; r < 4; ++r)
            xv[r] = *(const float4*)&X[(size_t)(row0 + r) * NF + k];
        #pragma unroll
        for (int kk = 0; kk < 4; ++kk) {
            float wv[8];
            #pragma unroll
            for (int c = 0; c < 8; ++c) wv[c] = Ws[(k + kk) * NF + col0 + c];
            #pragma unroll
            for (int r = 0; r < 4; ++r) {
                float x = (kk == 0) ? xv[r].x : (kk == 1) ? xv[r].y
                        : (kk == 2) ? xv[r].z : xv[r].w;
                #pragma unroll
                for (int c = 0; c < 8; ++c) acc[r][c] += x * wv[c];
            }
        }
    }

    #pragma unroll
    for (int r = 0; r < 4; ++r) {
        float out[8];
        #pragma unroll
        for (int c = 0; c < 8; ++c) {
            float v = acc[r][c] + b[col0 + c];
            out[c] = fmaxf(v, 0.0f);
        }
        float* yp = &Y[(size_t)(row0 + r) * NF + col0];
        *(float4*)&yp[0] = *(float4*)&out[0];
        *(float4*)&yp[4] = *(float4*)&out[4];
    }
}

// ---------------------------------------------------------------------------
// Mean pool over nodes + 2-layer MLP readout. One block (256 thr) per graph.
// ---------------------------------------------------------------------------
__global__ __launch_bounds__(256) void pool_readout_kernel(
    const float* __restrict__ Y,
    const float* __restrict__ Wr1, const float* __restrict__ br1,
    const float* __restrict__ Wr2, const float* __restrict__ br2,
    float* __restrict__ out)
{
    __shared__ float partial[256];
    __shared__ float hsh[NF];
    __shared__ float r1[64];

    int g = blockIdx.x;
    int t = threadIdx.x;
    int f = t & (NF - 1);
    int half = t >> 7;

    const float* base = Y + (size_t)g * NN * NF;
    float s = 0.0f;
    for (int r = half * 256; r < half * 256 + 256; ++r)
        s += base[(size_t)r * NF + f];
    partial[t] = s;
    __syncthreads();

    if (t < NF) hsh[t] = (partial[t] + partial[t + NF]) * (1.0f / (float)NN);
    __syncthreads();

    if (t < 64) {
        float a = br1[t];
        #pragma unroll 8
        for (int k = 0; k < NF; ++k) a += hsh[k] * Wr1[k * 64 + t];
        r1[t] = fmaxf(a, 0.0f);
    }
    __syncthreads();

    if (t < 64) {
        float v = r1[t] * Wr2[t];
        #pragma unroll
        for (int off = 32; off; off >>= 1) v += __shfl_down(v, off);
        if (t == 0) out[g] = v + br2[0];
    }
}

// ---------------------------------------------------------------------------
extern "C" void kernel_launch(void* const* d_in, const int* in_sizes, int n_in,
                              void* d_out, int out_size, void* d_ws, size_t ws_size,
                              hipStream_t stream)
{
    const float* X    = (const float*)d_in[0];
    // d_in[1] = batch (unused; nodes already grouped per graph)
    const int*   ei   = (const int*)d_in[2];
    const float* W1   = (const float*)d_in[3];
    const float* b1   = (const float*)d_in[4];
    const float* W2   = (const float*)d_in[5];
    const float* b2   = (const float*)d_in[6];
    const float* Wr1  = (const float*)d_in[7];
    const float* br1  = (const float*)d_in[8];
    const float* Wr2  = (const float*)d_in[9];
    const float* br2  = (const float*)d_in[10];
    float* out = (float*)d_out;

    const int* src = ei;
    const int* dst = ei + NE;

    // workspace layout
    char* ws = (char*)d_ws;
    unsigned* bitmap = (unsigned*)ws;                         // 4 MB
    int*      deg    = (int*)(ws + (size_t)4 * 1024 * 1024);  // 256 KB
    float*    dinv   = (float*)(ws + (size_t)4 * 1024 * 1024 + 256 * 1024);
    float*    buf0   = (float*)(ws + (size_t)4608 * 1024);    // acc, 32 MB
    float*    buf1   = (float*)(ws + (size_t)(4608 + 32768) * 1024);
    float*    buf2   = (float*)(ws + (size_t)(4608 + 65536) * 1024);

    // zero bitmap + deg (4 MB + 256 KB contiguous)
    hipMemsetAsync(d_ws, 0, (size_t)4 * 1024 * 1024 + 256 * 1024, stream);

    build_adj_kernel<<<NE / 256, 256, 0, stream>>>(src, dst, bitmap, deg);
    dinv_kernel<<<BN / 256, 256, 0, stream>>>(deg, dinv);

    // ---- Layer 1: acc = X + SX + S^2X + S^3X ; y1 = relu(acc@W1+b1) -> buf1
    spmm_kernel<<<BN, 128, 0, stream>>>(X,    buf1, buf0, X,    bitmap, dinv, 1);
    spmm_kernel<<<BN, 128, 0, stream>>>(buf1, buf2, buf0, X,    bitmap, dinv, 0);
    spmm_kernel<<<BN, 128, 0, stream>>>(buf2, buf1, buf0, X,    bitmap, dinv, 0);
    gemm_bias_relu_kernel<<<BN / 64, 256, 0, stream>>>(buf0, W1, b1, buf1);

    // ---- Layer 2: acc = y1 + Sy1 + S^2y1 + S^3y1 ; y2 = relu(acc@W2+b2) -> buf1
    spmm_kernel<<<BN, 128, 0, stream>>>(buf1, buf2, buf0, buf1, bitmap, dinv, 1);
    spmm_kernel<<<BN, 128, 0, stream>>>(buf2, buf1, buf0, buf1, bitmap, dinv, 0);
    spmm_kernel<<<BN, 128, 0, stream>>>(buf1, buf2, buf0, buf1, bitmap, dinv, 0);
    gemm_bias_relu_kernel<<<BN / 64, 256, 0, stream>>>(buf0, W2, b2, buf1);

    // ---- Pool + readout
    pool_readout_kernel<<<NB, 256, 0, stream>>>(buf1, Wr1, br1, Wr2, br2, out);
}

// Round 2
// 551.717 us; speedup vs baseline: 1.7586x; 1.7586x over previous
//
#include <hip/hip_runtime.h>
#include <hip/hip_bf16.h>

// Problem constants (match reference)
#define NB 128          // graphs
#define NN 512          // nodes per graph
#define NF 128          // feature dim
#define BN (NB*NN)      // 65536 total nodes
#define NE (BN*16)      // 1048576 edges
#define WPR 16          // bitmap words per row (512 bits / 32)
#define STRIDE 36       // LDS floats per row (32 + 4 pad -> spreads banks)

// ---------------------------------------------------------------------------
// Adjacency build: bitmap with set-semantics dedup + out-degree count
// ---------------------------------------------------------------------------
__global__ __launch_bounds__(256) void build_adj_kernel(
    const int* __restrict__ src, const int* __restrict__ dst,
    unsigned* __restrict__ bitmap, int* __restrict__ deg)
{
    int e = blockIdx.x * 256 + threadIdx.x;
    int s = src[e];
    int d = dst[e];
    int col = d & (NN - 1);                 // column within graph
    unsigned word = (unsigned)s * WPR + (col >> 5);
    unsigned mask = 1u << (col & 31);
    unsigned old = atomicOr(&bitmap[word], mask);
    if (!(old & mask)) atomicAdd(&deg[s], 1);
}

__global__ __launch_bounds__(256) void dinv_kernel(
    const int* __restrict__ deg, float* __restrict__ dinv)
{
    int i = blockIdx.x * 256 + threadIdx.x;
    int d = deg[i];
    dinv[i] = (d > 0) ? rsqrtf((float)d) : 0.0f;
}

// ---------------------------------------------------------------------------
// Fused 3-hop poly conv for one (graph, feature-quarter):
//   acc = x + Sx + S^2x + S^3x      written to accout
// z kept in LDS double-buffer (full graph, 32 features), acc in registers.
// One block = 256 threads; thread t owns rows t and t+256.
// ---------------------------------------------------------------------------
__global__ __launch_bounds__(256, 1) void poly_fused_kernel(
    const float* __restrict__ xin,      // [BN, NF]
    float* __restrict__ accout,         // [BN, NF]
    const uint4* __restrict__ bmp,      // [BN*4] (16 words/row)
    const float* __restrict__ dinv)
{
    extern __shared__ float lds[];
    float* zA  = lds;                       // 512*STRIDE
    float* zB  = lds + NN * STRIDE;         // 512*STRIDE
    float* dsh = lds + 2 * NN * STRIDE;     // 512

    int b = blockIdx.x;
    // XCD-locality swizzle: 4 quarter-blocks of a graph land on one XCD
    int xcd  = b & 7;
    int slot = b >> 3;
    int g = xcd * 16 + (slot >> 2);
    int q = slot & 3;
    int t = threadIdx.x;

    const float* xg = xin + (size_t)g * NN * NF + q * 32;

    // dinv for this graph -> LDS
    dsh[t]       = dinv[g * NN + t];
    dsh[t + 256] = dinv[g * NN + t + 256];

    // cooperative coalesced load: x quarter -> zA
    for (int i = t; i < NN * 8; i += 256) {
        int r = i >> 3, sg = i & 7;
        float4 v = *(const float4*)&xg[(size_t)r * NF + sg * 4];
        *(float4*)&zA[r * STRIDE + sg * 4] = v;
    }
    __syncthreads();

    int r0 = t, r1 = t + 256;
    float acc0[32], acc1[32];
    #pragma unroll
    for (int k8 = 0; k8 < 8; ++k8) {
        float4 a = *(float4*)&zA[r0 * STRIDE + k8 * 4];
        acc0[k8*4+0] = a.x; acc0[k8*4+1] = a.y; acc0[k8*4+2] = a.z; acc0[k8*4+3] = a.w;
        float4 c = *(float4*)&zB[0];  // dummy to keep types; overwritten below
        (void)c;
        float4 e = *(float4*)&zA[r1 * STRIDE + k8 * 4];
        acc1[k8*4+0] = e.x; acc1[k8*4+1] = e.y; acc1[k8*4+2] = e.z; acc1[k8*4+3] = e.w;
    }

    float* zc = zA;
    float* zn = zB;

    for (int hop = 0; hop < 3; ++hop) {
        // ---- row r0
        {
            float s[32];
            #pragma unroll
            for (int k = 0; k < 32; ++k) s[k] = 0.0f;
            #pragma unroll
            for (int w4 = 0; w4 < 4; ++w4) {
                uint4 bw = bmp[(size_t)(g * NN + r0) * 4 + w4];
                unsigned wv[4] = {bw.x, bw.y, bw.z, bw.w};
                #pragma unroll
                for (int wi = 0; wi < 4; ++wi) {
                    unsigned bits = wv[wi];
                    int cb = (w4 * 4 + wi) * 32;
                    while (bits) {
                        int j = __ffs(bits) - 1;
                        bits &= bits - 1;
                        int nbr = cb + j;
                        float dj = dsh[nbr];
                        const float* zr = &zc[nbr * STRIDE];
                        #pragma unroll
                        for (int k8 = 0; k8 < 8; ++k8) {
                            float4 zv = *(const float4*)&zr[k8 * 4];
                            s[k8*4+0] += dj * zv.x;
                            s[k8*4+1] += dj * zv.y;
                            s[k8*4+2] += dj * zv.z;
                            s[k8*4+3] += dj * zv.w;
                        }
                    }
                }
            }
            float di = dsh[r0];
            #pragma unroll
            for (int k8 = 0; k8 < 8; ++k8) {
                float4 v;
                v.x = di * s[k8*4+0]; v.y = di * s[k8*4+1];
                v.z = di * s[k8*4+2]; v.w = di * s[k8*4+3];
                acc0[k8*4+0] += v.x; acc0[k8*4+1] += v.y;
                acc0[k8*4+2] += v.z; acc0[k8*4+3] += v.w;
                *(float4*)&zn[r0 * STRIDE + k8 * 4] = v;
            }
        }
        // ---- row r1
        {
            float s[32];
            #pragma unroll
            for (int k = 0; k < 32; ++k) s[k] = 0.0f;
            #pragma unroll
            for (int w4 = 0; w4 < 4; ++w4) {
                uint4 bw = bmp[(size_t)(g * NN + r1) * 4 + w4];
                unsigned wv[4] = {bw.x, bw.y, bw.z, bw.w};
                #pragma unroll
                for (int wi = 0; wi < 4; ++wi) {
                    unsigned bits = wv[wi];
                    int cb = (w4 * 4 + wi) * 32;
                    while (bits) {
                        int j = __ffs(bits) - 1;
                        bits &= bits - 1;
                        int nbr = cb + j;
                        float dj = dsh[nbr];
                        const float* zr = &zc[nbr * STRIDE];
                        #pragma unroll
                        for (int k8 = 0; k8 < 8; ++k8) {
                            float4 zv = *(const float4*)&zr[k8 * 4];
                            s[k8*4+0] += dj * zv.x;
                            s[k8*4+1] += dj * zv.y;
                            s[k8*4+2] += dj * zv.z;
                            s[k8*4+3] += dj * zv.w;
                        }
                    }
                }
            }
            float di = dsh[r1];
            #pragma unroll
            for (int k8 = 0; k8 < 8; ++k8) {
                float4 v;
                v.x = di * s[k8*4+0]; v.y = di * s[k8*4+1];
                v.z = di * s[k8*4+2]; v.w = di * s[k8*4+3];
                acc1[k8*4+0] += v.x; acc1[k8*4+1] += v.y;
                acc1[k8*4+2] += v.z; acc1[k8*4+3] += v.w;
                *(float4*)&zn[r1 * STRIDE + k8 * 4] = v;
            }
        }
        __syncthreads();
        float* tmp = zc; zc = zn; zn = tmp;
    }

    // write acc (x + z1 + z2 + z3) to global
    float* og = accout + (size_t)g * NN * NF + q * 32;
    #pragma unroll
    for (int k8 = 0; k8 < 8; ++k8) {
        float4 v0, v1;
        v0.x = acc0[k8*4+0]; v0.y = acc0[k8*4+1]; v0.z = acc0[k8*4+2]; v0.w = acc0[k8*4+3];
        v1.x = acc1[k8*4+0]; v1.y = acc1[k8*4+1]; v1.z = acc1[k8*4+2]; v1.w = acc1[k8*4+3];
        *(float4*)&og[(size_t)r0 * NF + k8 * 4] = v0;
        *(float4*)&og[(size_t)r1 * NF + k8 * 4] = v1;
    }
}

// ---------------------------------------------------------------------------
// GEMM: Y[65536,128] = relu(X @ W[128,128] + b)
// block: 256 threads, 64 rows x 128 cols per block; thread: 4 rows x 8 cols
// ---------------------------------------------------------------------------
__global__ __launch_bounds__(256) void gemm_bias_relu_kernel(
    const float* __restrict__ X, const float* __restrict__ W,
    const float* __restrict__ b, float* __restrict__ Y)
{
    __shared__ float Ws[NF * NF];
    for (int i = threadIdx.x; i < NF * NF / 4; i += 256) {
        ((float4*)Ws)[i] = ((const float4*)W)[i];
    }
    __syncthreads();

    int rg = threadIdx.x >> 4;              // 0..15
    int cg = threadIdx.x & 15;              // 0..15
    int row0 = blockIdx.x * 64 + rg * 4;
    int col0 = cg * 8;

    float acc[4][8];
    #pragma unroll
    for (int r = 0; r < 4; ++r)
        #pragma unroll
        for (int c = 0; c < 8; ++c) acc[r][c] = 0.0f;

    for (int k = 0; k < NF; k += 4) {
        float4 xv[4];
        #pragma unroll
        for (int r = 0; r < 4; ++r)
            xv[r] = *(const float4*)&X[(size_t)(row0 + r) * NF + k];
        #pragma unroll
        for (int kk = 0; kk < 4; ++kk) {
            float wv[8];
            #pragma unroll
            for (int c = 0; c < 8; ++c) wv[c] = Ws[(k + kk) * NF + col0 + c];
            #pragma unroll
            for (int r = 0; r < 4; ++r) {
                float x = (kk == 0) ? xv[r].x : (kk == 1) ? xv[r].y
                        : (kk == 2) ? xv[r].z : xv[r].w;
                #pragma unroll
                for (int c = 0; c < 8; ++c) acc[r][c] += x * wv[c];
            }
        }
    }

    #pragma unroll
    for (int r = 0; r < 4; ++r) {
        float out[8];
        #pragma unroll
        for (int c = 0; c < 8; ++c) {
            float v = acc[r][c] + b[col0 + c];
            out[c] = fmaxf(v, 0.0f);
        }
        float* yp = &Y[(size_t)(row0 + r) * NF + col0];
        *(float4*)&yp[0] = *(float4*)&out[0];
        *(float4*)&yp[4] = *(float4*)&out[4];
    }
}

// ---------------------------------------------------------------------------
// Mean pool over nodes + 2-layer MLP readout. One block (256 thr) per graph.
// ---------------------------------------------------------------------------
__global__ __launch_bounds__(256) void pool_readout_kernel(
    const float* __restrict__ Y,
    const float* __restrict__ Wr1, const float* __restrict__ br1,
    const float* __restrict__ Wr2, const float* __restrict__ br2,
    float* __restrict__ out)
{
    __shared__ float partial[256];
    __shared__ float hsh[NF];
    __shared__ float r1[64];

    int g = blockIdx.x;
    int t = threadIdx.x;
    int f = t & (NF - 1);
    int half = t >> 7;

    const float* base = Y + (size_t)g * NN * NF;
    float s = 0.0f;
    for (int r = half * 256; r < half * 256 + 256; ++r)
        s += base[(size_t)r * NF + f];
    partial[t] = s;
    __syncthreads();

    if (t < NF) hsh[t] = (partial[t] + partial[t + NF]) * (1.0f / (float)NN);
    __syncthreads();

    if (t < 64) {
        float a = br1[t];
        #pragma unroll 8
        for (int k = 0; k < NF; ++k) a += hsh[k] * Wr1[k * 64 + t];
        r1[t] = fmaxf(a, 0.0f);
    }
    __syncthreads();

    if (t < 64) {
        float v = r1[t] * Wr2[t];
        #pragma unroll
        for (int off = 32; off; off >>= 1) v += __shfl_down(v, off);
        if (t == 0) out[g] = v + br2[0];
    }
}

// ---------------------------------------------------------------------------
extern "C" void kernel_launch(void* const* d_in, const int* in_sizes, int n_in,
                              void* d_out, int out_size, void* d_ws, size_t ws_size,
                              hipStream_t stream)
{
    const float* X    = (const float*)d_in[0];
    // d_in[1] = batch (unused; nodes already grouped per graph)
    const int*   ei   = (const int*)d_in[2];
    const float* W1   = (const float*)d_in[3];
    const float* b1   = (const float*)d_in[4];
    const float* W2   = (const float*)d_in[5];
    const float* b2   = (const float*)d_in[6];
    const float* Wr1  = (const float*)d_in[7];
    const float* br1  = (const float*)d_in[8];
    const float* Wr2  = (const float*)d_in[9];
    const float* br2  = (const float*)d_in[10];
    float* out = (float*)d_out;

    const int* src = ei;
    const int* dst = ei + NE;

    // workspace layout
    char* ws = (char*)d_ws;
    unsigned* bitmap = (unsigned*)ws;                         // 4 MB
    int*      deg    = (int*)(ws + (size_t)4 * 1024 * 1024);  // 256 KB
    float*    dinv   = (float*)(ws + (size_t)4 * 1024 * 1024 + 256 * 1024);
    float*    buf0   = (float*)(ws + (size_t)4608 * 1024);    // acc, 32 MB
    float*    buf1   = (float*)(ws + (size_t)(4608 + 32768) * 1024);

    // zero bitmap + deg (4 MB + 256 KB contiguous)
    hipMemsetAsync(d_ws, 0, (size_t)4 * 1024 * 1024 + 256 * 1024, stream);

    build_adj_kernel<<<NE / 256, 256, 0, stream>>>(src, dst, bitmap, deg);
    dinv_kernel<<<BN / 256, 256, 0, stream>>>(deg, dinv);

    const size_t LDSSZ = (2 * NN * STRIDE + NN) * sizeof(float);  // 149504 B

    // ---- Layer 1
    poly_fused_kernel<<<NB * 4, 256, LDSSZ, stream>>>(X, buf0, (const uint4*)bitmap, dinv);
    gemm_bias_relu_kernel<<<BN / 64, 256, 0, stream>>>(buf0, W1, b1, buf1);

    // ---- Layer 2
    poly_fused_kernel<<<NB * 4, 256, LDSSZ, stream>>>(buf1, buf0, (const uint4*)bitmap, dinv);
    gemm_bias_relu_kernel<<<BN / 64, 256, 0, stream>>>(buf0, W2, b2, buf1);

    // ---- Pool + readout
    pool_readout_kernel<<<NB, 256, 0, stream>>>(buf1, Wr1, br1, Wr2, br2, out);
}